// Round 18
// baseline (51.768 us; speedup 1.0000x reference)
//
#include <hip/hip_runtime.h>

// Problem constants: B=8, N=2048, M=2048, D=128
#define B_DIM 8
#define N_DIM 2048
#define M_DIM 2048
#define D_DIM 128
#define NT_TILES 4

typedef __bf16 bf16_t;
typedef bf16_t bf16x8 __attribute__((ext_vector_type(8)));
typedef float f32x4 __attribute__((ext_vector_type(4)));
typedef float f32x16 __attribute__((ext_vector_type(16)));

// lgkm-only barrier: never drains vmcnt -> global stores / prefetch loads
// stay in flight across tile boundaries.
__device__ __forceinline__ void lgkm_barrier() {
    asm volatile("s_waitcnt lgkmcnt(0)" ::: "memory");
    __builtin_amdgcn_s_barrier();
}

// ---------------------------------------------------------------------------
// R11 champion (32x32x16 MFMA s-outer 4-acc, full-line stores, fused staging,
// XCD-batch swizzle, lgkm-only barriers, prefetch-before-stores) +
// PHASE-STAGGERED TILE ORDER (convoy breaking):
//
// All 512 blocks are co-resident and symmetric -> chip-wide lockstep: every
// block's store burst and MFMA window align, so the HBM write stream pulses
// and the write pipe idles between bursts. Rotating each block's tile visit
// order by ph = ((w>>8)&1)*2 + ((w>>6)&1) puts the two blocks sharing a CU
// (w and w+256) in ANTIPHASE (offset 2 tiles) and alternates phase across
// CU groups: one block stores while its CU-partner runs MFMA.
// Each block still writes the same 4 tiles, just in rotated order.
// ---------------------------------------------------------------------------
__global__ __launch_bounds__(256, 2) void fused_dist_kernel(
    const float* __restrict__ L, const float* __restrict__ R,
    float* __restrict__ out)
{
    __shared__ bf16x8 Als[2048];   // 32 KB
    __shared__ bf16x8 Bls[2048];   // 32 KB
    __shared__ float nAs[128];
    __shared__ float nBs[128];

    // ---- XCD-locality decode: one batch per XCD (blockIdx round-robins XCDs)
    const int w   = blockIdx.x;    // [0, 512)
    const int bz  = w & 7;         // XCD id == batch
    const int i   = w >> 3;        // [0, 64) within XCD
    const int bxg = i & 3;         // covers NT_TILES bx tiles
    const int by  = i >> 2;        // [0, 16)
    // phase: CU partners (w, w+256) antiphase; CU groups alternate
    const int ph  = ((w >> 8) & 1) * 2 + ((w >> 6) & 1);

    const int tid  = threadIdx.x;
    const int wid  = tid >> 6;
    const int lane = tid & 63;
    const int rA   = lane & 15;        // row within 16-row LDS group
    const int g2   = (lane >> 4) & 1;  // which 16-row group within 32
    const int hi   = lane >> 5;        // 0..1 (K-half / row-offset select)
    const int c32  = lane & 31;        // fragment row/col within 32
    const int r    = tid >> 4;         // staging: row within 16-row group
    const int gran = tid & 15;         // staging: 8-elem chunk

    const float* Asrc = L + ((size_t)bz * N_DIM + (size_t)by * 128) * D_DIM;
    const float* Rbat = R + (size_t)bz * M_DIM * D_DIM;

    // ---- initial stage: A panel (bf16 RNE + norms from SAME rounded values)
    #pragma unroll
    for (int i2 = 0; i2 < 8; ++i2) {
        int row = i2 * 16 + r;
        float4 v0 = ((const float4*)Asrc)[(size_t)row * 32 + gran * 2];
        float4 v1 = ((const float4*)Asrc)[(size_t)row * 32 + gran * 2 + 1];
        bf16x8 p = { (bf16_t)v0.x, (bf16_t)v0.y, (bf16_t)v0.z, (bf16_t)v0.w,
                     (bf16_t)v1.x, (bf16_t)v1.y, (bf16_t)v1.z, (bf16_t)v1.w };
        Als[i2 * 256 + gran * 16 + (r ^ gran)] = p;
        float s = 0.0f;
        #pragma unroll
        for (int j = 0; j < 8; ++j) { float x = (float)p[j]; s = fmaf(x, x, s); }
        s += __shfl_xor(s, 1); s += __shfl_xor(s, 2);
        s += __shfl_xor(s, 4); s += __shfl_xor(s, 8);
        if (gran == 0) nAs[i2 * 16 + r] = s;
    }
    // ---- initial stage: B tile `ph`
    {
        const float* Bsrc = Rbat + (size_t)(bxg * NT_TILES + ph) * 128 * D_DIM;
        #pragma unroll
        for (int i2 = 0; i2 < 8; ++i2) {
            int row = i2 * 16 + r;
            float4 v0 = ((const float4*)Bsrc)[(size_t)row * 32 + gran * 2];
            float4 v1 = ((const float4*)Bsrc)[(size_t)row * 32 + gran * 2 + 1];
            bf16x8 p = { (bf16_t)v0.x, (bf16_t)v0.y, (bf16_t)v0.z, (bf16_t)v0.w,
                         (bf16_t)v1.x, (bf16_t)v1.y, (bf16_t)v1.z, (bf16_t)v1.w };
            Bls[i2 * 256 + gran * 16 + (r ^ gran)] = p;
            float s = 0.0f;
            #pragma unroll
            for (int j = 0; j < 8; ++j) { float x = (float)p[j]; s = fmaf(x, x, s); }
            s += __shfl_xor(s, 1); s += __shfl_xor(s, 2);
            s += __shfl_xor(s, 4); s += __shfl_xor(s, 8);
            if (gran == 0) nBs[i2 * 16 + r] = s;
        }
    }
    lgkm_barrier();

    // ---- wave tile bases: each wave owns 64x64 = 2x2 of 32x32 MFMA tiles
    const int wM = (wid >> 1) * 64;
    const int wN = (wid & 1) * 64;

    // ---- A fragments into registers (Als dead afterwards): af[tm][s]
    bf16x8 af[2][8];
    #pragma unroll
    for (int s = 0; s < 8; ++s) {
        const int gr = s * 2 + hi;           // 16B k-granule
        #pragma unroll
        for (int tm = 0; tm < 2; ++tm) {
            const int grp = (wM >> 4) + tm * 2 + g2;
            af[tm][s] = Als[grp * 256 + gr * 16 + (rA ^ gr)];
        }
    }

    // ---- tile loop (visit order rotated by ph)
    for (int t = 0; t < NT_TILES; ++t) {
        const int tt = (t + ph) & 3;
        const int bx = bxg * NT_TILES + tt;

        // 1. MFMA on current B tile (8 K-steps of 16)
        f32x16 acc[2][2] = {};
        #pragma unroll
        for (int s = 0; s < 8; ++s) {
            const int gr = s * 2 + hi;
            bf16x8 bfr[2];
            #pragma unroll
            for (int tn = 0; tn < 2; ++tn) {
                const int grp = (wN >> 4) + tn * 2 + g2;
                bfr[tn] = Bls[grp * 256 + gr * 16 + (rA ^ gr)];
            }
            #pragma unroll
            for (int tm = 0; tm < 2; ++tm)
                #pragma unroll
                for (int tn = 0; tn < 2; ++tn)
                    acc[tm][tn] = __builtin_amdgcn_mfma_f32_32x32x16_bf16(
                        af[tm][s], bfr[tn], acc[tm][tn], 0, 0, 0);
        }

        // 2. prefetch next B tile (f32) into regs BEFORE any stores issue
        float4 pf0[8], pf1[8];
        if (t + 1 < NT_TILES) {
            const float* Bsrc =
                Rbat + (size_t)(bxg * NT_TILES + ((tt + 1) & 3)) * 128 * D_DIM;
            #pragma unroll
            for (int i2 = 0; i2 < 8; ++i2) {
                int row = i2 * 16 + r;
                pf0[i2] = ((const float4*)Bsrc)[(size_t)row * 32 + gran * 2];
                pf1[i2] = ((const float4*)Bsrc)[(size_t)row * 32 + gran * 2 + 1];
            }
        }

        // 3. epilogue + full-line stores
        //    out-row = wM + tm*32 + g*8 + hi*4 + e,  out-col = wN + tn*32 + c32
        const size_t outBase =
            ((size_t)bz * N_DIM + (size_t)by * 128) * M_DIM + (size_t)bx * 128;
        #pragma unroll
        for (int tm = 0; tm < 2; ++tm) {
            #pragma unroll
            for (int tn = 0; tn < 2; ++tn) {
                const int col_l = wN + tn * 32 + c32;
                const float r2 = nBs[col_l];
                float* ocol = out + outBase + col_l;
                #pragma unroll
                for (int g = 0; g < 4; ++g) {
                    const int rowb = wM + tm * 32 + g * 8 + hi * 4;
                    const f32x4 l2q = *(const f32x4*)&nAs[rowb];
                    #pragma unroll
                    for (int e = 0; e < 4; ++e) {
                        float d2 = fmaf(-2.0f, acc[tm][tn][g * 4 + e],
                                        l2q[e] + r2);
                        d2 = fmaxf(d2, 0.0f);
                        float sq = __builtin_amdgcn_sqrtf(d2);
                        ocol[(size_t)(rowb + e) * M_DIM] =
                            __builtin_amdgcn_rcpf(1.0f + sq);
                    }
                }
            }
        }

        // 4. restage next B tile from prefetched regs (lgkm-only barriers)
        if (t + 1 < NT_TILES) {
            lgkm_barrier();                    // all waves done reading Bls/nBs
            #pragma unroll
            for (int i2 = 0; i2 < 8; ++i2) {
                bf16x8 p = { (bf16_t)pf0[i2].x, (bf16_t)pf0[i2].y,
                             (bf16_t)pf0[i2].z, (bf16_t)pf0[i2].w,
                             (bf16_t)pf1[i2].x, (bf16_t)pf1[i2].y,
                             (bf16_t)pf1[i2].z, (bf16_t)pf1[i2].w };
                Bls[i2 * 256 + gran * 16 + (r ^ gran)] = p;
                float s = 0.0f;
                #pragma unroll
                for (int j = 0; j < 8; ++j) { float x = (float)p[j]; s = fmaf(x, x, s); }
                s += __shfl_xor(s, 1); s += __shfl_xor(s, 2);
                s += __shfl_xor(s, 4); s += __shfl_xor(s, 8);
                if (gran == 0) nBs[i2 * 16 + r] = s;
            }
            lgkm_barrier();                    // staging visible
        }
    }
}

extern "C" void kernel_launch(void* const* d_in, const int* in_sizes, int n_in,
                              void* d_out, int out_size, void* d_ws, size_t ws_size,
                              hipStream_t stream) {
    const float* L = (const float*)d_in[0];
    const float* R = (const float*)d_in[1];
    float* out = (float*)d_out;

    // 1D grid: w&7 selects XCD (round-robin) == batch; 64 blocks per XCD.
    dim3 grid(512, 1, 1);
    dim3 block(256);
    fused_dist_kernel<<<grid, block, 0, stream>>>(L, R, out);
}

// Round 19
// 39.142 us; speedup vs baseline: 1.3226x; 1.3226x over previous
//
#include <hip/hip_runtime.h>

// Problem constants: B=8, N=2048, M=2048, D=128
#define B_DIM 8
#define N_DIM 2048
#define M_DIM 2048
#define D_DIM 128
#define NT_TILES 4

typedef __bf16 bf16_t;
typedef bf16_t bf16x8 __attribute__((ext_vector_type(8)));
typedef float f32x4 __attribute__((ext_vector_type(4)));
typedef float f32x16 __attribute__((ext_vector_type(16)));

// lgkm-only barrier: never drains vmcnt -> global stores / prefetch loads
// stay in flight across tile boundaries.
__device__ __forceinline__ void lgkm_barrier() {
    asm volatile("s_waitcnt lgkmcnt(0)" ::: "memory");
    __builtin_amdgcn_s_barrier();
}

// ---------------------------------------------------------------------------
// R11 champion (32x32x16 MFMA s-outer 4-acc, full-line stores, fused staging,
// XCD-batch swizzle, lgkm-only barriers, prefetch-before-stores) with
// NONTEMPORAL OUTPUT STORES:
//
// The 134MB output is write-once-never-read, but normal stores allocate in
// L2: the output stream sweeps each 4MB XCD-L2, evicting the input panels
// (FETCH 40-51MB vs 17MB compulsory) and doubling L2 internal traffic
// (allocate + dirty-evict). `nt` stores bypass L2 allocation: writes stream
// to HBM, L2 stays reserved for the input panels.
// ---------------------------------------------------------------------------
__global__ __launch_bounds__(256, 2) void fused_dist_kernel(
    const float* __restrict__ L, const float* __restrict__ R,
    float* __restrict__ out)
{
    __shared__ bf16x8 Als[2048];   // 32 KB
    __shared__ bf16x8 Bls[2048];   // 32 KB
    __shared__ float nAs[128];
    __shared__ float nBs[128];

    // ---- XCD-locality decode: one batch per XCD (blockIdx round-robins XCDs)
    const int w   = blockIdx.x;    // [0, 512)
    const int bz  = w & 7;         // XCD id == batch
    const int i   = w >> 3;        // [0, 64) within XCD
    const int bxg = i & 3;         // covers NT_TILES bx tiles
    const int by  = i >> 2;        // [0, 16)

    const int tid  = threadIdx.x;
    const int wid  = tid >> 6;
    const int lane = tid & 63;
    const int rA   = lane & 15;        // row within 16-row LDS group
    const int g2   = (lane >> 4) & 1;  // which 16-row group within 32
    const int hi   = lane >> 5;        // 0..1 (K-half / row-offset select)
    const int c32  = lane & 31;        // fragment row/col within 32
    const int r    = tid >> 4;         // staging: row within 16-row group
    const int gran = tid & 15;         // staging: 8-elem chunk

    const float* Asrc = L + ((size_t)bz * N_DIM + (size_t)by * 128) * D_DIM;
    const float* Rbat = R + (size_t)bz * M_DIM * D_DIM;

    // ---- initial stage: A panel (bf16 RNE + norms from SAME rounded values)
    #pragma unroll
    for (int i2 = 0; i2 < 8; ++i2) {
        int row = i2 * 16 + r;
        float4 v0 = ((const float4*)Asrc)[(size_t)row * 32 + gran * 2];
        float4 v1 = ((const float4*)Asrc)[(size_t)row * 32 + gran * 2 + 1];
        bf16x8 p = { (bf16_t)v0.x, (bf16_t)v0.y, (bf16_t)v0.z, (bf16_t)v0.w,
                     (bf16_t)v1.x, (bf16_t)v1.y, (bf16_t)v1.z, (bf16_t)v1.w };
        Als[i2 * 256 + gran * 16 + (r ^ gran)] = p;
        float s = 0.0f;
        #pragma unroll
        for (int j = 0; j < 8; ++j) { float x = (float)p[j]; s = fmaf(x, x, s); }
        s += __shfl_xor(s, 1); s += __shfl_xor(s, 2);
        s += __shfl_xor(s, 4); s += __shfl_xor(s, 8);
        if (gran == 0) nAs[i2 * 16 + r] = s;
    }
    // ---- initial stage: B tile 0
    {
        const float* Bsrc = Rbat + (size_t)(bxg * NT_TILES) * 128 * D_DIM;
        #pragma unroll
        for (int i2 = 0; i2 < 8; ++i2) {
            int row = i2 * 16 + r;
            float4 v0 = ((const float4*)Bsrc)[(size_t)row * 32 + gran * 2];
            float4 v1 = ((const float4*)Bsrc)[(size_t)row * 32 + gran * 2 + 1];
            bf16x8 p = { (bf16_t)v0.x, (bf16_t)v0.y, (bf16_t)v0.z, (bf16_t)v0.w,
                         (bf16_t)v1.x, (bf16_t)v1.y, (bf16_t)v1.z, (bf16_t)v1.w };
            Bls[i2 * 256 + gran * 16 + (r ^ gran)] = p;
            float s = 0.0f;
            #pragma unroll
            for (int j = 0; j < 8; ++j) { float x = (float)p[j]; s = fmaf(x, x, s); }
            s += __shfl_xor(s, 1); s += __shfl_xor(s, 2);
            s += __shfl_xor(s, 4); s += __shfl_xor(s, 8);
            if (gran == 0) nBs[i2 * 16 + r] = s;
        }
    }
    lgkm_barrier();

    // ---- wave tile bases: each wave owns 64x64 = 2x2 of 32x32 MFMA tiles
    const int wM = (wid >> 1) * 64;
    const int wN = (wid & 1) * 64;

    // ---- A fragments into registers (Als dead afterwards): af[tm][s]
    bf16x8 af[2][8];
    #pragma unroll
    for (int s = 0; s < 8; ++s) {
        const int gr = s * 2 + hi;           // 16B k-granule
        #pragma unroll
        for (int tm = 0; tm < 2; ++tm) {
            const int grp = (wM >> 4) + tm * 2 + g2;
            af[tm][s] = Als[grp * 256 + gr * 16 + (rA ^ gr)];
        }
    }

    // ---- tile loop
    for (int t = 0; t < NT_TILES; ++t) {
        const int bx = bxg * NT_TILES + t;

        // 1. MFMA on current B tile (8 K-steps of 16)
        f32x16 acc[2][2] = {};
        #pragma unroll
        for (int s = 0; s < 8; ++s) {
            const int gr = s * 2 + hi;
            bf16x8 bfr[2];
            #pragma unroll
            for (int tn = 0; tn < 2; ++tn) {
                const int grp = (wN >> 4) + tn * 2 + g2;
                bfr[tn] = Bls[grp * 256 + gr * 16 + (rA ^ gr)];
            }
            #pragma unroll
            for (int tm = 0; tm < 2; ++tm)
                #pragma unroll
                for (int tn = 0; tn < 2; ++tn)
                    acc[tm][tn] = __builtin_amdgcn_mfma_f32_32x32x16_bf16(
                        af[tm][s], bfr[tn], acc[tm][tn], 0, 0, 0);
        }

        // 2. prefetch next B tile (f32) into regs BEFORE any stores issue
        float4 pf0[8], pf1[8];
        if (t + 1 < NT_TILES) {
            const float* Bsrc = Rbat + (size_t)(bx + 1) * 128 * D_DIM;
            #pragma unroll
            for (int i2 = 0; i2 < 8; ++i2) {
                int row = i2 * 16 + r;
                pf0[i2] = ((const float4*)Bsrc)[(size_t)row * 32 + gran * 2];
                pf1[i2] = ((const float4*)Bsrc)[(size_t)row * 32 + gran * 2 + 1];
            }
        }

        // 3. epilogue + full-line NONTEMPORAL stores
        //    out-row = wM + tm*32 + g*8 + hi*4 + e,  out-col = wN + tn*32 + c32
        const size_t outBase =
            ((size_t)bz * N_DIM + (size_t)by * 128) * M_DIM + (size_t)bx * 128;
        #pragma unroll
        for (int tm = 0; tm < 2; ++tm) {
            #pragma unroll
            for (int tn = 0; tn < 2; ++tn) {
                const int col_l = wN + tn * 32 + c32;
                const float r2 = nBs[col_l];
                float* ocol = out + outBase + col_l;
                #pragma unroll
                for (int g = 0; g < 4; ++g) {
                    const int rowb = wM + tm * 32 + g * 8 + hi * 4;
                    const f32x4 l2q = *(const f32x4*)&nAs[rowb];
                    #pragma unroll
                    for (int e = 0; e < 4; ++e) {
                        float d2 = fmaf(-2.0f, acc[tm][tn][g * 4 + e],
                                        l2q[e] + r2);
                        d2 = fmaxf(d2, 0.0f);
                        float sq = __builtin_amdgcn_sqrtf(d2);
                        float o = __builtin_amdgcn_rcpf(1.0f + sq);
                        __builtin_nontemporal_store(
                            o, ocol + (size_t)(rowb + e) * M_DIM);
                    }
                }
            }
        }

        // 4. restage next B tile from prefetched regs (lgkm-only barriers)
        if (t + 1 < NT_TILES) {
            lgkm_barrier();                    // all waves done reading Bls/nBs
            #pragma unroll
            for (int i2 = 0; i2 < 8; ++i2) {
                bf16x8 p = { (bf16_t)pf0[i2].x, (bf16_t)pf0[i2].y,
                             (bf16_t)pf0[i2].z, (bf16_t)pf0[i2].w,
                             (bf16_t)pf1[i2].x, (bf16_t)pf1[i2].y,
                             (bf16_t)pf1[i2].z, (bf16_t)pf1[i2].w };
                Bls[i2 * 256 + gran * 16 + (r ^ gran)] = p;
                float s = 0.0f;
                #pragma unroll
                for (int j = 0; j < 8; ++j) { float x = (float)p[j]; s = fmaf(x, x, s); }
                s += __shfl_xor(s, 1); s += __shfl_xor(s, 2);
                s += __shfl_xor(s, 4); s += __shfl_xor(s, 8);
                if (gran == 0) nBs[i2 * 16 + r] = s;
            }
            lgkm_barrier();                    // staging visible
        }
    }
}

extern "C" void kernel_launch(void* const* d_in, const int* in_sizes, int n_in,
                              void* d_out, int out_size, void* d_ws, size_t ws_size,
                              hipStream_t stream) {
    const float* L = (const float*)d_in[0];
    const float* R = (const float*)d_in[1];
    float* out = (float*)d_out;

    // 1D grid: w&7 selects XCD (round-robin) == batch; 64 blocks per XCD.
    dim3 grid(512, 1, 1);
    dim3 block(256);
    fused_dist_kernel<<<grid, block, 0, stream>>>(L, R, out);
}